// Round 4
// baseline (140.104 us; speedup 1.0000x reference)
//
#include <hip/hip_runtime.h>
#include <hip/hip_bf16.h>
#include <math.h>
#include <stdint.h>

#define BATCH 2
#define NH 12
#define SEQ 2048
#define HD 64
#define TQ 64
#define TK 64
#define NHEADS (BATCH*NH)
#define NIT (SEQ / TK)

typedef short bf16x8 __attribute__((ext_vector_type(8)));
typedef float f32x4 __attribute__((ext_vector_type(4)));
typedef unsigned short us8_t __attribute__((ext_vector_type(8)));

#if __has_builtin(__builtin_amdgcn_exp2f)
#define EXP2F(x) __builtin_amdgcn_exp2f(x)
#else
#define EXP2F(x) exp2f(x)
#endif

static __device__ __forceinline__ unsigned short f2bf(float f) {
    unsigned int u = __float_as_uint(f);
    u += 0x7fffu + ((u >> 16) & 1u);   // RTNE
    return (unsigned short)(u >> 16);
}

static __device__ __forceinline__ unsigned int pack2bf(float a, float b) {
    __hip_bfloat162 v = __float22bfloat162_rn(float2{a, b});
    return *(unsigned int*)&v;          // low short = a, high short = b
}

static __device__ __forceinline__ void async_cp16(const void* g, void* l) {
    __builtin_amdgcn_global_load_lds(
        (const __attribute__((address_space(1))) void*)g,
        (__attribute__((address_space(3))) void*)(uintptr_t)l,
        16, 0, 0);
}

// ---- pre-pass: Q (pre-scaled) + K -> bf16, V -> bf16 transposed [bh][d][s] ----
__global__ __launch_bounds__(256)
void prep_qkv(const float* __restrict__ Q, const float* __restrict__ K,
              const float* __restrict__ V,
              unsigned short* __restrict__ Qb, unsigned short* __restrict__ Kb,
              unsigned short* __restrict__ Vtb, float qs) {
    const int bh = blockIdx.x >> 5;
    const int s0 = (blockIdx.x & 31) * 64;
    const int tid = threadIdx.x;
    const size_t off = ((size_t)bh * SEQ + s0) * HD;

    #pragma unroll
    for (int i = 0; i < 2; ++i) {
        size_t e0 = off + (size_t)(tid + 256 * i) * 8;
        float4 a = *(const float4*)&Q[e0];
        float4 b = *(const float4*)&Q[e0 + 4];
        us8_t rq = { f2bf(a.x*qs), f2bf(a.y*qs), f2bf(a.z*qs), f2bf(a.w*qs),
                     f2bf(b.x*qs), f2bf(b.y*qs), f2bf(b.z*qs), f2bf(b.w*qs) };
        *(us8_t*)&Qb[e0] = rq;
        float4 c = *(const float4*)&K[e0];
        float4 d = *(const float4*)&K[e0 + 4];
        us8_t rk = { f2bf(c.x), f2bf(c.y), f2bf(c.z), f2bf(c.w),
                     f2bf(d.x), f2bf(d.y), f2bf(d.z), f2bf(d.w) };
        *(us8_t*)&Kb[e0] = rk;
    }

    // V transpose: lane = n (coalesced 2B stores), cg picks d-group
    const float* Vsrc = V + off;
    unsigned short* Vdst = Vtb + (size_t)bh * HD * SEQ;
    const int n  = tid & 63;
    const int cg = tid >> 6;
    #pragma unroll
    for (int i = 0; i < 4; ++i) {
        int c4 = (cg + 4 * i) * 4;
        float4 v = *(const float4*)&Vsrc[(size_t)n * HD + c4];
        Vdst[(size_t)(c4 + 0) * SEQ + s0 + n] = f2bf(v.x);
        Vdst[(size_t)(c4 + 1) * SEQ + s0 + n] = f2bf(v.y);
        Vdst[(size_t)(c4 + 2) * SEQ + s0 + n] = f2bf(v.z);
        Vdst[(size_t)(c4 + 3) * SEQ + s0 + n] = f2bf(v.w);
    }
}

// ---------------- main flash-attention kernel ----------------
// 128 threads = 2 waves, each wave owns 32 q-rows. S^T = K.Q^T so P writes pack to b64.
__global__ __launch_bounds__(128)
void fa_main(const unsigned short* __restrict__ Qb,
             const unsigned short* __restrict__ Kb,
             const unsigned short* __restrict__ Vtb,
             float* __restrict__ O) {
    const int x  = blockIdx.x & 7;
    const int t  = blockIdx.x >> 3;
    const int bh = x + 8 * (t % 3);
    const int qt = t / 3;
    const int q0 = qt * TQ;

    __shared__ unsigned short Ks[TK * HD];       // 8 KB, XOR-swizzled 16B chunks
    __shared__ unsigned short Vs[HD * TK];       // 8 KB, V^T rows (d major)
    __shared__ unsigned short QP[2 * 32 * 72];   // union: Q staging (64x64) / Ps[2][32][72]
    __shared__ float Lw[2][32];

    const int tid  = threadIdx.x;
    const int w    = tid >> 6;
    const int lane = tid & 63;
    const int col  = lane & 15;
    const int quad = lane >> 4;
    const int r8   = lane >> 3;
    const int c8   = lane & 7;
    const int swz  = col & 7;

    const unsigned short* Qh = Qb  + ((size_t)bh * SEQ + q0) * HD;
    const unsigned short* Kh = Kb  + (size_t)bh * SEQ * HD;
    const unsigned short* Vh = Vtb + (size_t)bh * HD * SEQ;

    // ---- prologue: stage Q (into QP) + K/V tile 0, all async ----
    #pragma unroll
    for (int i = 0; i < 4; ++i) {
        const int R = w * 32 + i * 8;
        async_cp16(Qh + (size_t)(R + r8) * HD + (c8 ^ r8) * 8, &QP[R * HD]);
    }
    #pragma unroll
    for (int i = 0; i < 4; ++i) {
        const int R = w * 32 + i * 8;
        async_cp16(Kh + (size_t)(R + r8) * HD + (c8 ^ r8) * 8, &Ks[R * HD]);
        async_cp16(Vh + (size_t)(R + r8) * SEQ + (c8 ^ r8) * 8, &Vs[R * HD]);
    }
    __syncthreads();

    // ---- Q B-fragments (rows w*32 .. w*32+31) -> registers, then free QP ----
    bf16x8 qf[2][2];
    #pragma unroll
    for (int mt = 0; mt < 2; ++mt)
        #pragma unroll
        for (int ks = 0; ks < 2; ++ks)
            qf[mt][ks] = *(const bf16x8*)&QP[(w*32 + mt*16 + col) * HD + (((ks*4 + quad) ^ swz) * 8)];
    __syncthreads();   // everyone done reading Q before Ps overwrites QP

    unsigned short* Psw = &QP[w * 2304];   // this wave's P tile: [32][72]

    f32x4 o[2][4];
    #pragma unroll
    for (int mt = 0; mt < 2; ++mt)
        #pragma unroll
        for (int dt = 0; dt < 4; ++dt) o[mt][dt] = (f32x4){0.f, 0.f, 0.f, 0.f};
    float lsum[2] = {0.f, 0.f};

    for (int it = 0; it < NIT; ++it) {
        // ---- QK^T as S^T = K.Q^T : tiles [nt 0..3][mt 0..1] ----
        f32x4 sc[2][4];
        #pragma unroll
        for (int nt = 0; nt < 4; ++nt) {
            const int kr = (nt*16 + col) * HD;
            bf16x8 kf0 = *(const bf16x8*)&Ks[kr + (((0*4 + quad) ^ swz) * 8)];
            bf16x8 kf1 = *(const bf16x8*)&Ks[kr + (((1*4 + quad) ^ swz) * 8)];
            #pragma unroll
            for (int mt = 0; mt < 2; ++mt) {
                f32x4 z = {0.f, 0.f, 0.f, 0.f};
                z = __builtin_amdgcn_mfma_f32_16x16x32_bf16(kf0, qf[mt][0], z, 0, 0, 0);
                z = __builtin_amdgcn_mfma_f32_16x16x32_bf16(kf1, qf[mt][1], z, 0, 0, 0);
                sc[mt][nt] = z;
            }
        }

        // ---- exp2, packed b64 P writes (S^T layout: fixed m per lane, n along regs) ----
        #pragma unroll
        for (int mt = 0; mt < 2; ++mt) {
            #pragma unroll
            for (int nt = 0; nt < 4; ++nt) {
                float p0 = EXP2F(sc[mt][nt][0]);
                float p1 = EXP2F(sc[mt][nt][1]);
                float p2 = EXP2F(sc[mt][nt][2]);
                float p3 = EXP2F(sc[mt][nt][3]);
                lsum[mt] += (p0 + p1) + (p2 + p3);
                uint2 pk = { pack2bf(p0, p1), pack2bf(p2, p3) };
                *(uint2*)&Psw[(mt*16 + col) * 72 + nt*16 + quad*4] = pk;
            }
        }

        // ---- PV: O[m][d] += P.V (A = P rows, B = V^T rows), wave-private ----
        bf16x8 pf[2][2];
        #pragma unroll
        for (int mt = 0; mt < 2; ++mt)
            #pragma unroll
            for (int ks = 0; ks < 2; ++ks)
                pf[mt][ks] = *(const bf16x8*)&Psw[(mt*16 + col) * 72 + ks*32 + quad*8];
        #pragma unroll
        for (int dt = 0; dt < 4; ++dt) {
            const int vr = (dt*16 + col) * HD;
            bf16x8 vf0 = *(const bf16x8*)&Vs[vr + (((0*4 + quad) ^ swz) * 8)];
            bf16x8 vf1 = *(const bf16x8*)&Vs[vr + (((1*4 + quad) ^ swz) * 8)];
            #pragma unroll
            for (int mt = 0; mt < 2; ++mt) {
                o[mt][dt] = __builtin_amdgcn_mfma_f32_16x16x32_bf16(pf[mt][0], vf0, o[mt][dt], 0, 0, 0);
                o[mt][dt] = __builtin_amdgcn_mfma_f32_16x16x32_bf16(pf[mt][1], vf1, o[mt][dt], 0, 0, 0);
            }
        }

        // ---- stage next K/V tile (single buffer, 2 barriers) ----
        __syncthreads();   // all waves done reading Ks/Vs
        if (it + 1 < NIT) {
            const int kv0 = (it + 1) * TK;
            #pragma unroll
            for (int i = 0; i < 4; ++i) {
                const int R = w * 32 + i * 8;
                async_cp16(Kh + (size_t)(kv0 + R + r8) * HD  + (c8 ^ r8) * 8, &Ks[R * HD]);
                async_cp16(Vh + (size_t)(R + r8) * SEQ + kv0 + (c8 ^ r8) * 8, &Vs[R * HD]);
            }
        }
        __syncthreads();   // tiles resident
    }

    // ---- epilogue: finish row sums (reduce across quads), normalize, store ----
    #pragma unroll
    for (int mt = 0; mt < 2; ++mt) {
        lsum[mt] += __shfl_xor(lsum[mt], 16, 64);
        lsum[mt] += __shfl_xor(lsum[mt], 32, 64);
    }
    if (quad == 0) {
        Lw[w][col]      = lsum[0];
        Lw[w][16 + col] = lsum[1];
    }
    // same-wave LDS RAW: ordered, no barrier needed
    float* Oh = O + ((size_t)bh * SEQ + q0 + w*32) * HD;
    #pragma unroll
    for (int mt = 0; mt < 2; ++mt) {
        #pragma unroll
        for (int r = 0; r < 4; ++r) {
            const int row = mt*16 + quad*4 + r;
            float inv = 1.0f / Lw[w][row];
            #pragma unroll
            for (int dt = 0; dt < 4; ++dt)
                Oh[(size_t)row * HD + dt*16 + col] = o[mt][dt][r] * inv;
        }
    }
}

// ---------------- fallback (no-workspace) kernel ----------------
#define PAD 8
#define LSTR (HD + PAD)

__global__ __launch_bounds__(256)
void fa_fwd_fb(const float* __restrict__ Q, const float* __restrict__ K,
               const float* __restrict__ V, float* __restrict__ O) {
    const int x  = blockIdx.x & 7;
    const int t  = blockIdx.x >> 3;
    const int bh = x + 8 * (t % 3);
    const int qt = t / 3;
    const int q0 = qt * TQ;
    const long base = (long)bh * SEQ * HD;

    __shared__ unsigned short Qs[TQ][LSTR];
    __shared__ unsigned short Ks2[TK][LSTR];
    __shared__ unsigned short Vt[HD][TK + PAD];
    __shared__ unsigned short Ps2[4][16][LSTR];

    const int tid  = threadIdx.x;
    const int wave = tid >> 6;
    const int lane = tid & 63;
    const int col  = lane & 15;
    const int quad = lane >> 4;
    const int m0   = wave * 16;

    #pragma unroll
    for (int i = 0; i < 4; ++i) {
        int idx = tid + 256 * i;
        int row = idx >> 4;
        int c4  = (idx & 15) * 4;
        float4 v = *(const float4*)&Q[base + (long)(q0 + row) * HD + c4];
        ushort4 b = { f2bf(v.x), f2bf(v.y), f2bf(v.z), f2bf(v.w) };
        *(ushort4*)&Qs[row][c4] = b;
    }
    __syncthreads();

    bf16x8 aq0 = *(const bf16x8*)&Qs[m0 + col][quad * 8];
    bf16x8 aq1 = *(const bf16x8*)&Qs[m0 + col][32 + quad * 8];

    f32x4 o0 = {0.f,0.f,0.f,0.f}, o1 = o0, o2 = o0, o3 = o0;
    float l[4] = {0.f, 0.f, 0.f, 0.f};
    const float scale = 0.022097086912079608f;

    for (int kv0 = 0; kv0 < SEQ; kv0 += TK) {
        __syncthreads();
        #pragma unroll
        for (int i = 0; i < 4; ++i) {
            int idx = tid + 256 * i;
            int row = idx >> 4;
            int c4  = (idx & 15) * 4;
            float4 kv = *(const float4*)&K[base + (long)(kv0 + row) * HD + c4];
            ushort4 kb = { f2bf(kv.x), f2bf(kv.y), f2bf(kv.z), f2bf(kv.w) };
            *(ushort4*)&Ks2[row][c4] = kb;
            float4 vv = *(const float4*)&V[base + (long)(kv0 + row) * HD + c4];
            Vt[c4 + 0][row] = f2bf(vv.x);
            Vt[c4 + 1][row] = f2bf(vv.y);
            Vt[c4 + 2][row] = f2bf(vv.z);
            Vt[c4 + 3][row] = f2bf(vv.w);
        }
        __syncthreads();

        f32x4 sc[4];
        #pragma unroll
        for (int n = 0; n < 4; ++n) {
            bf16x8 b0 = *(const bf16x8*)&Ks2[n * 16 + col][quad * 8];
            bf16x8 b1 = *(const bf16x8*)&Ks2[n * 16 + col][32 + quad * 8];
            f32x4 acc = {0.f,0.f,0.f,0.f};
            acc = __builtin_amdgcn_mfma_f32_16x16x32_bf16(aq0, b0, acc, 0, 0, 0);
            acc = __builtin_amdgcn_mfma_f32_16x16x32_bf16(aq1, b1, acc, 0, 0, 0);
            sc[n] = acc;
        }

        float tsum[4] = {0.f, 0.f, 0.f, 0.f};
        #pragma unroll
        for (int n = 0; n < 4; ++n) {
            #pragma unroll
            for (int r = 0; r < 4; ++r) {
                float p = __expf(sc[n][r] * scale);
                tsum[r] += p;
                Ps2[wave][quad * 4 + r][n * 16 + col] = f2bf(p);
            }
        }
        #pragma unroll
        for (int off = 1; off < 16; off <<= 1) {
            #pragma unroll
            for (int r = 0; r < 4; ++r) tsum[r] += __shfl_xor(tsum[r], off, 64);
        }
        #pragma unroll
        for (int r = 0; r < 4; ++r) l[r] += tsum[r];

        bf16x8 ap0 = *(const bf16x8*)&Ps2[wave][col][quad * 8];
        bf16x8 ap1 = *(const bf16x8*)&Ps2[wave][col][32 + quad * 8];
        #pragma unroll
        for (int n = 0; n < 4; ++n) {
            bf16x8 b0 = *(const bf16x8*)&Vt[n * 16 + col][quad * 8];
            bf16x8 b1 = *(const bf16x8*)&Vt[n * 16 + col][32 + quad * 8];
            f32x4* op = (n == 0) ? &o0 : (n == 1) ? &o1 : (n == 2) ? &o2 : &o3;
            *op = __builtin_amdgcn_mfma_f32_16x16x32_bf16(ap0, b0, *op, 0, 0, 0);
            *op = __builtin_amdgcn_mfma_f32_16x16x32_bf16(ap1, b1, *op, 0, 0, 0);
        }
    }

    float inv[4];
    #pragma unroll
    for (int r = 0; r < 4; ++r) inv[r] = 1.0f / l[r];
    #pragma unroll
    for (int r = 0; r < 4; ++r) {
        long row = base + (long)(q0 + m0 + quad * 4 + r) * HD;
        O[row +  0 + col] = o0[r] * inv[r];
        O[row + 16 + col] = o1[r] * inv[r];
        O[row + 32 + col] = o2[r] * inv[r];
        O[row + 48 + col] = o3[r] * inv[r];
    }
}

extern "C" void kernel_launch(void* const* d_in, const int* in_sizes, int n_in,
                              void* d_out, int out_size, void* d_ws, size_t ws_size,
                              hipStream_t stream) {
    const float* Q = (const float*)d_in[0];
    const float* K = (const float*)d_in[1];
    const float* V = (const float*)d_in[2];
    float* O = (float*)d_out;

    const size_t tensorElems = (size_t)NHEADS * SEQ * HD;
    const size_t need = 3 * tensorElems * sizeof(unsigned short);

    if (ws_size >= need) {
        unsigned short* Qb  = (unsigned short*)d_ws;
        unsigned short* Kb  = Qb + tensorElems;
        unsigned short* Vtb = Kb + tensorElems;
        const float qs = (float)(1.4426950408889634 / sqrt(2048.0));  // log2e/sqrt(S)
        prep_qkv<<<dim3(NHEADS * (SEQ / 64)), dim3(256), 0, stream>>>(Q, K, V, Qb, Kb, Vtb, qs);
        fa_main<<<dim3(NHEADS * (SEQ / TQ)), dim3(128), 0, stream>>>(Qb, Kb, Vtb, O);
    } else {
        fa_fwd_fb<<<dim3(NHEADS * (SEQ / TQ)), dim3(256), 0, stream>>>(Q, K, V, O);
    }
}

// Round 5
// 126.482 us; speedup vs baseline: 1.1077x; 1.1077x over previous
//
#include <hip/hip_runtime.h>
#include <hip/hip_bf16.h>
#include <math.h>
#include <stdint.h>

#define BATCH 2
#define NH 12
#define SEQ 2048
#define HD 64
#define TQ 64
#define TK 64
#define NHEADS (BATCH*NH)
#define NIT (SEQ / TK)

typedef short bf16x8 __attribute__((ext_vector_type(8)));
typedef float f32x4 __attribute__((ext_vector_type(4)));
typedef float f32x16 __attribute__((ext_vector_type(16)));
typedef unsigned short us8_t __attribute__((ext_vector_type(8)));

#if __has_builtin(__builtin_amdgcn_exp2f)
#define EXP2F(x) __builtin_amdgcn_exp2f(x)
#else
#define EXP2F(x) exp2f(x)
#endif

static __device__ __forceinline__ unsigned short f2bf(float f) {
    unsigned int u = __float_as_uint(f);
    u += 0x7fffu + ((u >> 16) & 1u);   // RTNE
    return (unsigned short)(u >> 16);
}

static __device__ __forceinline__ unsigned int pack2bf(float a, float b) {
    __hip_bfloat162 v = __float22bfloat162_rn(float2{a, b});
    return *(unsigned int*)&v;
}

static __device__ __forceinline__ void async_cp16(const void* g, void* l) {
    __builtin_amdgcn_global_load_lds(
        (const __attribute__((address_space(1))) void*)g,
        (__attribute__((address_space(3))) void*)(uintptr_t)l,
        16, 0, 0);
}

// ---- pre-pass: Q (pre-scaled) + K -> bf16, V -> bf16 transposed [bh][d][s] ----
__global__ __launch_bounds__(256)
void prep_qkv(const float* __restrict__ Q, const float* __restrict__ K,
              const float* __restrict__ V,
              unsigned short* __restrict__ Qb, unsigned short* __restrict__ Kb,
              unsigned short* __restrict__ Vtb, float qs) {
    const int bh = blockIdx.x >> 5;
    const int s0 = (blockIdx.x & 31) * 64;
    const int tid = threadIdx.x;
    const size_t off = ((size_t)bh * SEQ + s0) * HD;

    #pragma unroll
    for (int i = 0; i < 2; ++i) {
        size_t e0 = off + (size_t)(tid + 256 * i) * 8;
        float4 a = *(const float4*)&Q[e0];
        float4 b = *(const float4*)&Q[e0 + 4];
        us8_t rq = { f2bf(a.x*qs), f2bf(a.y*qs), f2bf(a.z*qs), f2bf(a.w*qs),
                     f2bf(b.x*qs), f2bf(b.y*qs), f2bf(b.z*qs), f2bf(b.w*qs) };
        *(us8_t*)&Qb[e0] = rq;
        float4 c = *(const float4*)&K[e0];
        float4 d = *(const float4*)&K[e0 + 4];
        us8_t rk = { f2bf(c.x), f2bf(c.y), f2bf(c.z), f2bf(c.w),
                     f2bf(d.x), f2bf(d.y), f2bf(d.z), f2bf(d.w) };
        *(us8_t*)&Kb[e0] = rk;
    }

    const float* Vsrc = V + off;
    unsigned short* Vdst = Vtb + (size_t)bh * HD * SEQ;
    const int n  = tid & 63;
    const int cg = tid >> 6;
    #pragma unroll
    for (int i = 0; i < 4; ++i) {
        int c4 = (cg + 4 * i) * 4;
        float4 v = *(const float4*)&Vsrc[(size_t)n * HD + c4];
        Vdst[(size_t)(c4 + 0) * SEQ + s0 + n] = f2bf(v.x);
        Vdst[(size_t)(c4 + 1) * SEQ + s0 + n] = f2bf(v.y);
        Vdst[(size_t)(c4 + 2) * SEQ + s0 + n] = f2bf(v.z);
        Vdst[(size_t)(c4 + 3) * SEQ + s0 + n] = f2bf(v.w);
    }
}

// ---------------- main flash-attention kernel (32x32x16 MFMA) ----------------
// 256 thr / 4 waves. Wave w = (mt = w>>1, nt = w&1) owns S^T quadrant
// [n: nt*32..+32][m: mt*32..+32]; P round-trip wave-private; partial-O over
// its n-range; cross-nt O reduction at epilogue. K/V double-buffered,
// 1 barrier per iter.
__global__ __launch_bounds__(256)
void fa_main(const unsigned short* __restrict__ Qb,
             const unsigned short* __restrict__ Kb,
             const unsigned short* __restrict__ Vtb,
             float* __restrict__ O) {
    const int x  = blockIdx.x & 7;
    const int t  = blockIdx.x >> 3;
    const int bh = x + 8 * (t % 3);
    const int qt = t / 3;
    const int q0 = qt * TQ;

    __shared__ unsigned short Ksh[2][TK * HD];   // 16 KB (buf1 doubles as Q staging)
    __shared__ unsigned short Vsh[2][HD * TK];   // 16 KB (d-major V^T tiles)
    __shared__ unsigned short Ps[TQ * TK];       // 8 KB, XOR-chunk-swizzled, row m
    __shared__ float Lsum[TQ];
    __shared__ float Linv[TQ];

    const int tid  = threadIdx.x;
    const int w    = tid >> 6;
    const int mt   = w >> 1;
    const int nt   = w & 1;
    const int lane = tid & 63;
    const int l31  = lane & 31;
    const int hi   = lane >> 5;       // k-chunk selector for 32x32 frags
    const int l7   = lane & 7;        // row&7 for XOR swizzle
    const int r8   = lane >> 3;
    const int c8   = lane & 7;

    const unsigned short* Qh = Qb  + ((size_t)bh * SEQ + q0) * HD;
    const unsigned short* Kh = Kb  + (size_t)bh * SEQ * HD;
    const unsigned short* Vh = Vtb + (size_t)bh * HD * SEQ;

    // ---- prologue: Q -> Ksh[1] (union), K/V tile 0 -> buf 0 ----
    {
        const int R = w * 16;
        async_cp16(Qh + (size_t)(R     + r8) * HD + (c8 ^ r8) * 8, &Ksh[1][ R      * HD]);
        async_cp16(Qh + (size_t)(R + 8 + r8) * HD + (c8 ^ r8) * 8, &Ksh[1][(R + 8) * HD]);
        async_cp16(Kh + (size_t)(R     + r8) * HD + (c8 ^ r8) * 8, &Ksh[0][ R      * HD]);
        async_cp16(Kh + (size_t)(R + 8 + r8) * HD + (c8 ^ r8) * 8, &Ksh[0][(R + 8) * HD]);
        async_cp16(Vh + (size_t)(R     + r8) * SEQ + (c8 ^ r8) * 8, &Vsh[0][ R      * HD]);
        async_cp16(Vh + (size_t)(R + 8 + r8) * SEQ + (c8 ^ r8) * 8, &Vsh[0][(R + 8) * HD]);
    }
    __syncthreads();

    // ---- Q B-fragments (rows mt*32..+32, all 4 k-steps) -> registers ----
    bf16x8 qf[4];
    #pragma unroll
    for (int s = 0; s < 4; ++s)
        qf[s] = *(const bf16x8*)&Ksh[1][(mt*32 + l31) * HD + (((s*2 + hi) ^ l7) * 8)];
    __syncthreads();   // Q extracted before buf1 gets K tile 1

    f32x16 o[2];
    o[0] = (f32x16)(0.f);
    o[1] = (f32x16)(0.f);
    float lsum = 0.f;

    for (int it = 0; it < NIT; ++it) {
        const int cur = it & 1;
        if (it + 1 < NIT) {      // prefetch next tile; full compute phase to land
            const int nb  = cur ^ 1;
            const int kv0 = (it + 1) * TK;
            const int R   = w * 16;
            async_cp16(Kh + (size_t)(kv0 + R     + r8) * HD  + (c8 ^ r8) * 8, &Ksh[nb][ R      * HD]);
            async_cp16(Kh + (size_t)(kv0 + R + 8 + r8) * HD  + (c8 ^ r8) * 8, &Ksh[nb][(R + 8) * HD]);
            async_cp16(Vh + (size_t)(R     + r8) * SEQ + kv0 + (c8 ^ r8) * 8, &Vsh[nb][ R      * HD]);
            async_cp16(Vh + (size_t)(R + 8 + r8) * SEQ + kv0 + (c8 ^ r8) * 8, &Vsh[nb][(R + 8) * HD]);
        }
        const unsigned short* Ks = Ksh[cur];
        const unsigned short* Vs = Vsh[cur];

        // ---- S^T quadrant = K(32x64) . Q^T(64x32): 4 MFMAs ----
        f32x16 sc = (f32x16)(0.f);
        #pragma unroll
        for (int s = 0; s < 4; ++s) {
            bf16x8 kf = *(const bf16x8*)&Ks[(nt*32 + l31) * HD + (((s*2 + hi) ^ l7) * 8)];
            sc = __builtin_amdgcn_mfma_f32_32x32x16_bf16(kf, qf[s], sc, 0, 0, 0);
        }

        // ---- exp2, lsum, P -> LDS (b64 packed, swizzled chunks) ----
        float e[16];
        #pragma unroll
        for (int r = 0; r < 16; ++r) e[r] = EXP2F(sc[r]);
        #pragma unroll
        for (int r = 0; r < 16; ++r) lsum += e[r];
        #pragma unroll
        for (int g = 0; g < 4; ++g) {
            // rows n = nt*32 + 8g + 4*hi + 0..3, col m fixed
            const int m = mt*32 + l31;
            const int ch = nt*4 + g;              // logical 8-short chunk
            uint2 pk = { pack2bf(e[4*g+0], e[4*g+1]), pack2bf(e[4*g+2], e[4*g+3]) };
            *(uint2*)&Ps[m * TK + ((ch ^ (m & 7)) * 8) + hi * 4] = pk;
        }

        // ---- PV partial: O[m:mt][d] += P[m][n:nt] . V[n:nt][d]: 4 MFMAs ----
        bf16x8 pf[2];
        #pragma unroll
        for (int ks = 0; ks < 2; ++ks) {
            const int m = mt*32 + l31;
            const int ch = nt*4 + ks*2 + hi;
            pf[ks] = *(const bf16x8*)&Ps[m * TK + ((ch ^ (m & 7)) * 8)];
        }
        #pragma unroll
        for (int dt = 0; dt < 2; ++dt) {
            const int d = dt*32 + l31;
            #pragma unroll
            for (int ks = 0; ks < 2; ++ks) {
                const int ch = nt*4 + ks*2 + hi;
                bf16x8 vf = *(const bf16x8*)&Vs[d * HD + ((ch ^ l7) * 8)];
                o[dt] = __builtin_amdgcn_mfma_f32_32x32x16_bf16(pf[ks], vf, o[dt], 0, 0, 0);
            }
        }

        __syncthreads();   // all reads of buf[cur] done; prefetch drained
    }

    // ---- epilogue: combine nt partials (O and lsum), normalize, store ----
    lsum += __shfl_xor(lsum, 32, 64);      // full-n-range sum for m = mt*32 + l31
    float* ORed = (float*)Ksh;             // 64 d rows x 64 m f32, chunk-swizzled

    if (nt == 1) {
        if (lane < 32) Lsum[mt*32 + lane] = lsum;
        #pragma unroll
        for (int dt = 0; dt < 2; ++dt) {
            const int d = dt*32 + l31;
            #pragma unroll
            for (int g = 0; g < 4; ++g) {
                const int m0 = mt*32 + 8*g + 4*hi;
                const int ph = (m0 >> 2) ^ (d & 15);
                float4 v = { o[dt][4*g+0], o[dt][4*g+1], o[dt][4*g+2], o[dt][4*g+3] };
                *(float4*)&ORed[d * 64 + ph * 4] = v;
            }
        }
    }
    __syncthreads();

    if (nt == 0) {
        float ltot = lsum + Lsum[mt*32 + l31];
        if (lane < 32) Linv[mt*32 + lane] = 1.0f / ltot;
        float* Oh = O + ((size_t)bh * SEQ + q0) * HD;
        #pragma unroll
        for (int dt = 0; dt < 2; ++dt) {
            const int d = dt*32 + l31;
            #pragma unroll
            for (int g = 0; g < 4; ++g) {
                const int m0 = mt*32 + 8*g + 4*hi;
                const int ph = (m0 >> 2) ^ (d & 15);
                float4 part = *(const float4*)&ORed[d * 64 + ph * 4];
                float4 inv4 = *(const float4*)&Linv[m0];
                const float* pp = (const float*)&part;
                const float* ii = (const float*)&inv4;
                #pragma unroll
                for (int j = 0; j < 4; ++j)
                    Oh[(size_t)(m0 + j) * HD + d] = (o[dt][4*g+j] + pp[j]) * ii[j];
            }
        }
    }
}

// ---------------- fallback (no-workspace) kernel ----------------
#define PAD 8
#define LSTR (HD + PAD)

__global__ __launch_bounds__(256)
void fa_fwd_fb(const float* __restrict__ Q, const float* __restrict__ K,
               const float* __restrict__ V, float* __restrict__ O) {
    const int x  = blockIdx.x & 7;
    const int t  = blockIdx.x >> 3;
    const int bh = x + 8 * (t % 3);
    const int qt = t / 3;
    const int q0 = qt * TQ;
    const long base = (long)bh * SEQ * HD;

    __shared__ unsigned short Qs[TQ][LSTR];
    __shared__ unsigned short Ks2[TK][LSTR];
    __shared__ unsigned short Vt[HD][TK + PAD];
    __shared__ unsigned short Ps2[4][16][LSTR];

    const int tid  = threadIdx.x;
    const int wave = tid >> 6;
    const int lane = tid & 63;
    const int col  = lane & 15;
    const int quad = lane >> 4;
    const int m0   = wave * 16;

    #pragma unroll
    for (int i = 0; i < 4; ++i) {
        int idx = tid + 256 * i;
        int row = idx >> 4;
        int c4  = (idx & 15) * 4;
        float4 v = *(const float4*)&Q[base + (long)(q0 + row) * HD + c4];
        ushort4 b = { f2bf(v.x), f2bf(v.y), f2bf(v.z), f2bf(v.w) };
        *(ushort4*)&Qs[row][c4] = b;
    }
    __syncthreads();

    bf16x8 aq0 = *(const bf16x8*)&Qs[m0 + col][quad * 8];
    bf16x8 aq1 = *(const bf16x8*)&Qs[m0 + col][32 + quad * 8];

    f32x4 o0 = {0.f,0.f,0.f,0.f}, o1 = o0, o2 = o0, o3 = o0;
    float l[4] = {0.f, 0.f, 0.f, 0.f};
    const float scale = 0.022097086912079608f;

    for (int kv0 = 0; kv0 < SEQ; kv0 += TK) {
        __syncthreads();
        #pragma unroll
        for (int i = 0; i < 4; ++i) {
            int idx = tid + 256 * i;
            int row = idx >> 4;
            int c4  = (idx & 15) * 4;
            float4 kv = *(const float4*)&K[base + (long)(kv0 + row) * HD + c4];
            ushort4 kb = { f2bf(kv.x), f2bf(kv.y), f2bf(kv.z), f2bf(kv.w) };
            *(ushort4*)&Ks2[row][c4] = kb;
            float4 vv = *(const float4*)&V[base + (long)(kv0 + row) * HD + c4];
            Vt[c4 + 0][row] = f2bf(vv.x);
            Vt[c4 + 1][row] = f2bf(vv.y);
            Vt[c4 + 2][row] = f2bf(vv.z);
            Vt[c4 + 3][row] = f2bf(vv.w);
        }
        __syncthreads();

        f32x4 sc[4];
        #pragma unroll
        for (int n = 0; n < 4; ++n) {
            bf16x8 b0 = *(const bf16x8*)&Ks2[n * 16 + col][quad * 8];
            bf16x8 b1 = *(const bf16x8*)&Ks2[n * 16 + col][32 + quad * 8];
            f32x4 acc = {0.f,0.f,0.f,0.f};
            acc = __builtin_amdgcn_mfma_f32_16x16x32_bf16(aq0, b0, acc, 0, 0, 0);
            acc = __builtin_amdgcn_mfma_f32_16x16x32_bf16(aq1, b1, acc, 0, 0, 0);
            sc[n] = acc;
        }

        float tsum[4] = {0.f, 0.f, 0.f, 0.f};
        #pragma unroll
        for (int n = 0; n < 4; ++n) {
            #pragma unroll
            for (int r = 0; r < 4; ++r) {
                float p = __expf(sc[n][r] * scale);
                tsum[r] += p;
                Ps2[wave][quad * 4 + r][n * 16 + col] = f2bf(p);
            }
        }
        #pragma unroll
        for (int off = 1; off < 16; off <<= 1) {
            #pragma unroll
            for (int r = 0; r < 4; ++r) tsum[r] += __shfl_xor(tsum[r], off, 64);
        }
        #pragma unroll
        for (int r = 0; r < 4; ++r) l[r] += tsum[r];

        bf16x8 ap0 = *(const bf16x8*)&Ps2[wave][col][quad * 8];
        bf16x8 ap1 = *(const bf16x8*)&Ps2[wave][col][32 + quad * 8];
        #pragma unroll
        for (int n = 0; n < 4; ++n) {
            bf16x8 b0 = *(const bf16x8*)&Vt[n * 16 + col][quad * 8];
            bf16x8 b1 = *(const bf16x8*)&Vt[n * 16 + col][32 + quad * 8];
            f32x4* op = (n == 0) ? &o0 : (n == 1) ? &o1 : (n == 2) ? &o2 : &o3;
            *op = __builtin_amdgcn_mfma_f32_16x16x32_bf16(ap0, b0, *op, 0, 0, 0);
            *op = __builtin_amdgcn_mfma_f32_16x16x32_bf16(ap1, b1, *op, 0, 0, 0);
        }
    }

    float inv[4];
    #pragma unroll
    for (int r = 0; r < 4; ++r) inv[r] = 1.0f / l[r];
    #pragma unroll
    for (int r = 0; r < 4; ++r) {
        long row = base + (long)(q0 + m0 + quad * 4 + r) * HD;
        O[row +  0 + col] = o0[r] * inv[r];
        O[row + 16 + col] = o1[r] * inv[r];
        O[row + 32 + col] = o2[r] * inv[r];
        O[row + 48 + col] = o3[r] * inv[r];
    }
}

extern "C" void kernel_launch(void* const* d_in, const int* in_sizes, int n_in,
                              void* d_out, int out_size, void* d_ws, size_t ws_size,
                              hipStream_t stream) {
    const float* Q = (const float*)d_in[0];
    const float* K = (const float*)d_in[1];
    const float* V = (const float*)d_in[2];
    float* O = (float*)d_out;

    const size_t tensorElems = (size_t)NHEADS * SEQ * HD;
    const size_t need = 3 * tensorElems * sizeof(unsigned short);

    if (ws_size >= need) {
        unsigned short* Qb  = (unsigned short*)d_ws;
        unsigned short* Kb  = Qb + tensorElems;
        unsigned short* Vtb = Kb + tensorElems;
        const float qs = (float)(1.4426950408889634 / sqrt(2048.0));  // log2e/sqrt(S)
        prep_qkv<<<dim3(NHEADS * (SEQ / 64)), dim3(256), 0, stream>>>(Q, K, V, Qb, Kb, Vtb, qs);
        fa_main<<<dim3(NHEADS * (SEQ / TQ)), dim3(256), 0, stream>>>(Qb, Kb, Vtb, O);
    } else {
        fa_fwd_fb<<<dim3(NHEADS * (SEQ / TQ)), dim3(256), 0, stream>>>(Q, K, V, O);
    }
}

// Round 6
// 125.588 us; speedup vs baseline: 1.1156x; 1.0071x over previous
//
#include <hip/hip_runtime.h>
#include <hip/hip_bf16.h>
#include <math.h>
#include <stdint.h>

#define BATCH 2
#define NH 12
#define SEQ 2048
#define HD 64
#define TQ 64
#define TK 64
#define NHEADS (BATCH*NH)
#define NIT (SEQ / TK)

typedef short bf16x8 __attribute__((ext_vector_type(8)));
typedef float f32x4 __attribute__((ext_vector_type(4)));
typedef float f32x16 __attribute__((ext_vector_type(16)));
typedef unsigned short us4_t __attribute__((ext_vector_type(4)));
typedef unsigned short us8_t __attribute__((ext_vector_type(8)));

#if __has_builtin(__builtin_amdgcn_exp2f)
#define EXP2F(x) __builtin_amdgcn_exp2f(x)
#else
#define EXP2F(x) exp2f(x)
#endif

static __device__ __forceinline__ unsigned short f2bf(float f) {
    unsigned int u = __float_as_uint(f);
    u += 0x7fffu + ((u >> 16) & 1u);   // RTNE
    return (unsigned short)(u >> 16);
}

static __device__ __forceinline__ unsigned int pack2bf(float a, float b) {
    __hip_bfloat162 v = __float22bfloat162_rn(float2{a, b});
    return *(unsigned int*)&v;
}

static __device__ __forceinline__ void async_cp16(const void* g, void* l) {
    __builtin_amdgcn_global_load_lds(
        (const __attribute__((address_space(1))) void*)g,
        (__attribute__((address_space(3))) void*)(uintptr_t)l,
        16, 0, 0);
}

// Conflict-free 64x64-bf16 tile layout: 32 row-pairs x 256B, 16 positions of
// 16B, pos = ((r&1)*8 | c) ^ ((r>>1)&15).  b128 fragment reads (32 rows, fixed
// chunk) hit every bank exactly the minimum number of times.
static __device__ __forceinline__ int tile_off(int r, int c) {   // shorts
    int rp  = r >> 1;
    int pos = (((r & 1) << 3) | c) ^ (rp & 15);
    return rp * 128 + pos * 8;
}

// ---- pre-pass: K -> bf16 (dense), V -> bf16 transposed [bh][d][s] ----
__global__ __launch_bounds__(256)
void prep_kv(const float* __restrict__ K, const float* __restrict__ V,
             unsigned short* __restrict__ Kb, unsigned short* __restrict__ Vtb) {
    __shared__ unsigned short T[64][66];
    const int bh = blockIdx.x >> 5;
    const int s0 = (blockIdx.x & 31) * 64;
    const int tid = threadIdx.x;
    const size_t off = ((size_t)bh * SEQ + s0) * HD;

    #pragma unroll
    for (int u = 0; u < 4; ++u) {                 // K: dense 16B loads, 8B stores
        int idx = u * 1024 + tid * 4;
        float4 a = *(const float4*)&K[off + idx];
        us4_t r4 = { f2bf(a.x), f2bf(a.y), f2bf(a.z), f2bf(a.w) };
        *(us4_t*)&Kb[off + idx] = r4;
    }
    #pragma unroll
    for (int u = 0; u < 4; ++u) {                 // V: dense loads -> padded LDS
        int idx = u * 1024 + tid * 4;
        int r = idx >> 6, col = idx & 63;
        float4 a = *(const float4*)&V[off + idx];
        *(unsigned int*)&T[r][col]     = pack2bf(a.x, a.y);
        *(unsigned int*)&T[r][col + 2] = pack2bf(a.z, a.w);
    }
    __syncthreads();
    unsigned short* Vdst = Vtb + (size_t)bh * HD * SEQ;
    const int g = tid & 7, dd = tid >> 3;         // dd 0..31
    #pragma unroll
    for (int h = 0; h < 2; ++h) {
        int d = dd + 32 * h;
        us8_t r8;
        #pragma unroll
        for (int j = 0; j < 8; ++j) r8[j] = T[g * 8 + j][d];
        *(us8_t*)&Vdst[(size_t)d * SEQ + s0 + g * 8] = r8;
    }
}

// ---------------- main flash-attention kernel (32x32x16 MFMA) ----------------
__global__ __launch_bounds__(256)
void fa_main(const float* __restrict__ Q,
             const unsigned short* __restrict__ Kb,
             const unsigned short* __restrict__ Vtb,
             float* __restrict__ O, float qs) {
    const int x  = blockIdx.x & 7;
    const int t  = blockIdx.x >> 3;
    const int bh = x + 8 * (t % 3);
    const int qt = t / 3;
    const int q0 = qt * TQ;

    __shared__ __align__(16) unsigned short KtS[2][4096];   // 16 KB
    __shared__ __align__(16) unsigned short VtS[2][4096];   // 16 KB
    __shared__ __align__(16) unsigned short Ps[4096];       // 8 KB (Q staging union)
    __shared__ float Lsum[64];
    __shared__ float Linv[64];

    const int tid  = threadIdx.x;
    const int w    = tid >> 6;
    const int mt   = w >> 1;
    const int nt   = w & 1;
    const int lane = tid & 63;
    const int l31  = lane & 31;
    const int hi   = lane >> 5;

    const float*          Qh = Q   + ((size_t)bh * SEQ + q0) * HD;
    const unsigned short* Kh = Kb  + (size_t)bh * SEQ * HD;
    const unsigned short* Vh = Vtb + (size_t)bh * HD * SEQ;

    // ---- per-lane staging source offsets (loop-invariant) ----
    int rS[2], cS[2];
    #pragma unroll
    for (int i = 0; i < 2; ++i) {
        int rp = w * 8 + 4 * i + (lane >> 4);
        int lc = (lane & 15) ^ (rp & 15);
        rS[i] = 2 * rp + (lc >> 3);
        cS[i] = lc & 7;
    }
    const int dst0 = (w * 8 + 0) * 128, dst1 = (w * 8 + 4) * 128;  // shorts
    const size_t kG0 = (size_t)rS[0] * HD  + cS[0] * 8;
    const size_t kG1 = (size_t)rS[1] * HD  + cS[1] * 8;
    const size_t vG0 = (size_t)rS[0] * SEQ + cS[0] * 8;
    const size_t vG1 = (size_t)rS[1] * SEQ + cS[1] * 8;

    // ---- prologue: stage K/V tile 0 (async) + Q (fp32 -> scaled bf16) ----
    async_cp16(Kh + kG0, &KtS[0][dst0]);
    async_cp16(Kh + kG1, &KtS[0][dst1]);
    async_cp16(Vh + vG0, &VtS[0][dst0]);
    async_cp16(Vh + vG1, &VtS[0][dst1]);
    #pragma unroll
    for (int u = 0; u < 4; ++u) {
        int idx = u * 1024 + tid * 4;
        int r = idx >> 6, col = idx & 63;
        float4 a = *(const float4*)&Qh[idx];
        uint2 pk = { pack2bf(a.x * qs, a.y * qs), pack2bf(a.z * qs, a.w * qs) };
        *(uint2*)&Ps[tile_off(r, col >> 3) + (col & 7)] = pk;
    }
    __syncthreads();   // Q visible, tile 0 resident (barrier drains vmcnt)

    // ---- Q B-fragments -> registers, then Ps is free for P round-trip ----
    bf16x8 qf[4];
    #pragma unroll
    for (int s = 0; s < 4; ++s)
        qf[s] = *(const bf16x8*)&Ps[tile_off(mt * 32 + l31, s * 2 + hi)];
    __syncthreads();

    // ---- hoisted per-lane LDS offsets (shorts) ----
    const int m = mt * 32 + l31;
    int kOffL[4], vOffL[2][2], pW[4], pR[2];
    #pragma unroll
    for (int s = 0; s < 4; ++s) kOffL[s] = tile_off(nt * 32 + l31, s * 2 + hi);
    #pragma unroll
    for (int dt = 0; dt < 2; ++dt)
        #pragma unroll
        for (int ks = 0; ks < 2; ++ks)
            vOffL[dt][ks] = tile_off(dt * 32 + l31, nt * 4 + ks * 2 + hi);
    #pragma unroll
    for (int g = 0; g < 4; ++g) pW[g] = tile_off(m, nt * 4 + g) + hi * 4;
    #pragma unroll
    for (int ks = 0; ks < 2; ++ks) pR[ks] = tile_off(m, nt * 4 + ks * 2 + hi);

    f32x16 o[2];
    o[0] = (f32x16)(0.f);
    o[1] = (f32x16)(0.f);
    float lsum = 0.f;

    for (int it = 0; it < NIT; ++it) {
        const int cur = it & 1;
        if (it + 1 < NIT) {            // prefetch next tile into other buffer
            const int nb = cur ^ 1;
            const size_t kv = (size_t)(it + 1) * TK;
            async_cp16(Kh + kv * HD + kG0, &KtS[nb][dst0]);
            async_cp16(Kh + kv * HD + kG1, &KtS[nb][dst1]);
            async_cp16(Vh + kv + vG0,      &VtS[nb][dst0]);
            async_cp16(Vh + kv + vG1,      &VtS[nb][dst1]);
        }
        const unsigned short* Ks = KtS[cur];
        const unsigned short* Vs = VtS[cur];

        // ---- S^T quadrant = K(32x64) . Q^T(64x32): 4 MFMAs ----
        f32x16 sc = (f32x16)(0.f);
        #pragma unroll
        for (int s = 0; s < 4; ++s) {
            bf16x8 kf = *(const bf16x8*)&Ks[kOffL[s]];
            sc = __builtin_amdgcn_mfma_f32_32x32x16_bf16(kf, qf[s], sc, 0, 0, 0);
        }

        // ---- exp2, lsum, P -> LDS (8B packed, conflict-free layout) ----
        #pragma unroll
        for (int g = 0; g < 4; ++g) {
            float p0 = EXP2F(sc[4*g+0]);
            float p1 = EXP2F(sc[4*g+1]);
            float p2 = EXP2F(sc[4*g+2]);
            float p3 = EXP2F(sc[4*g+3]);
            lsum += (p0 + p1) + (p2 + p3);
            uint2 pk = { pack2bf(p0, p1), pack2bf(p2, p3) };
            *(uint2*)&Ps[pW[g]] = pk;
        }

        // ---- PV partial: O[m][d] += P[m][n-half] . V[n-half][d]: 4 MFMAs ----
        bf16x8 pf0 = *(const bf16x8*)&Ps[pR[0]];
        bf16x8 pf1 = *(const bf16x8*)&Ps[pR[1]];
        #pragma unroll
        for (int dt = 0; dt < 2; ++dt) {
            bf16x8 vf0 = *(const bf16x8*)&Vs[vOffL[dt][0]];
            o[dt] = __builtin_amdgcn_mfma_f32_32x32x16_bf16(pf0, vf0, o[dt], 0, 0, 0);
            bf16x8 vf1 = *(const bf16x8*)&Vs[vOffL[dt][1]];
            o[dt] = __builtin_amdgcn_mfma_f32_32x32x16_bf16(pf1, vf1, o[dt], 0, 0, 0);
        }

        __syncthreads();   // reads of buf[cur] done; prefetch drained
    }

    // ---- epilogue: combine nt partials (O and lsum), normalize, store ----
    lsum += __shfl_xor(lsum, 32, 64);
    float* ORed = (float*)&KtS[0][0];      // 16 KB overlay (safe after final barrier)

    if (nt == 1) {
        if (lane < 32) Lsum[mt * 32 + lane] = lsum;
        #pragma unroll
        for (int dt = 0; dt < 2; ++dt) {
            const int d = dt * 32 + l31;
            #pragma unroll
            for (int g = 0; g < 4; ++g) {
                const int m0 = mt * 32 + 8 * g + 4 * hi;
                const int ph = (m0 >> 2) ^ (d & 15);
                float4 v = { o[dt][4*g+0], o[dt][4*g+1], o[dt][4*g+2], o[dt][4*g+3] };
                *(float4*)&ORed[d * 64 + ph * 4] = v;
            }
        }
    }
    __syncthreads();

    if (nt == 0) {
        float ltot = lsum + Lsum[mt * 32 + l31];
        if (lane < 32) Linv[mt * 32 + lane] = 1.0f / ltot;
        float* Oh = O + ((size_t)bh * SEQ + q0) * HD;
        #pragma unroll
        for (int dt = 0; dt < 2; ++dt) {
            const int d = dt * 32 + l31;
            #pragma unroll
            for (int g = 0; g < 4; ++g) {
                const int m0 = mt * 32 + 8 * g + 4 * hi;
                const int ph = (m0 >> 2) ^ (d & 15);
                float4 part = *(const float4*)&ORed[d * 64 + ph * 4];
                float4 inv4 = *(const float4*)&Linv[m0];
                const float* pp = (const float*)&part;
                const float* ii = (const float*)&inv4;
                #pragma unroll
                for (int j = 0; j < 4; ++j)
                    Oh[(size_t)(m0 + j) * HD + d] = (o[dt][4*g+j] + pp[j]) * ii[j];
            }
        }
    }
}

// ---------------- fallback (no-workspace) kernel ----------------
#define PAD 8
#define LSTR (HD + PAD)

__global__ __launch_bounds__(256)
void fa_fwd_fb(const float* __restrict__ Q, const float* __restrict__ K,
               const float* __restrict__ V, float* __restrict__ O) {
    const int x  = blockIdx.x & 7;
    const int t  = blockIdx.x >> 3;
    const int bh = x + 8 * (t % 3);
    const int qt = t / 3;
    const int q0 = qt * TQ;
    const long base = (long)bh * SEQ * HD;

    __shared__ unsigned short Qs[TQ][LSTR];
    __shared__ unsigned short Ks2[TK][LSTR];
    __shared__ unsigned short Vt[HD][TK + PAD];
    __shared__ unsigned short Ps2[4][16][LSTR];

    const int tid  = threadIdx.x;
    const int wave = tid >> 6;
    const int lane = tid & 63;
    const int col  = lane & 15;
    const int quad = lane >> 4;
    const int m0   = wave * 16;

    #pragma unroll
    for (int i = 0; i < 4; ++i) {
        int idx = tid + 256 * i;
        int row = idx >> 4;
        int c4  = (idx & 15) * 4;
        float4 v = *(const float4*)&Q[base + (long)(q0 + row) * HD + c4];
        ushort4 b = { f2bf(v.x), f2bf(v.y), f2bf(v.z), f2bf(v.w) };
        *(ushort4*)&Qs[row][c4] = b;
    }
    __syncthreads();

    bf16x8 aq0 = *(const bf16x8*)&Qs[m0 + col][quad * 8];
    bf16x8 aq1 = *(const bf16x8*)&Qs[m0 + col][32 + quad * 8];

    f32x4 o0 = {0.f,0.f,0.f,0.f}, o1 = o0, o2 = o0, o3 = o0;
    float l[4] = {0.f, 0.f, 0.f, 0.f};
    const float scale = 0.022097086912079608f;

    for (int kv0 = 0; kv0 < SEQ; kv0 += TK) {
        __syncthreads();
        #pragma unroll
        for (int i = 0; i < 4; ++i) {
            int idx = tid + 256 * i;
            int row = idx >> 4;
            int c4  = (idx & 15) * 4;
            float4 kv = *(const float4*)&K[base + (long)(kv0 + row) * HD + c4];
            ushort4 kb = { f2bf(kv.x), f2bf(kv.y), f2bf(kv.z), f2bf(kv.w) };
            *(ushort4*)&Ks2[row][c4] = kb;
            float4 vv = *(const float4*)&V[base + (long)(kv0 + row) * HD + c4];
            Vt[c4 + 0][row] = f2bf(vv.x);
            Vt[c4 + 1][row] = f2bf(vv.y);
            Vt[c4 + 2][row] = f2bf(vv.z);
            Vt[c4 + 3][row] = f2bf(vv.w);
        }
        __syncthreads();

        f32x4 sc[4];
        #pragma unroll
        for (int n = 0; n < 4; ++n) {
            bf16x8 b0 = *(const bf16x8*)&Ks2[n * 16 + col][quad * 8];
            bf16x8 b1 = *(const bf16x8*)&Ks2[n * 16 + col][32 + quad * 8];
            f32x4 acc = {0.f,0.f,0.f,0.f};
            acc = __builtin_amdgcn_mfma_f32_16x16x32_bf16(aq0, b0, acc, 0, 0, 0);
            acc = __builtin_amdgcn_mfma_f32_16x16x32_bf16(aq1, b1, acc, 0, 0, 0);
            sc[n] = acc;
        }

        float tsum[4] = {0.f, 0.f, 0.f, 0.f};
        #pragma unroll
        for (int n = 0; n < 4; ++n) {
            #pragma unroll
            for (int r = 0; r < 4; ++r) {
                float p = __expf(sc[n][r] * scale);
                tsum[r] += p;
                Ps2[wave][quad * 4 + r][n * 16 + col] = f2bf(p);
            }
        }
        #pragma unroll
        for (int off = 1; off < 16; off <<= 1) {
            #pragma unroll
            for (int r = 0; r < 4; ++r) tsum[r] += __shfl_xor(tsum[r], off, 64);
        }
        #pragma unroll
        for (int r = 0; r < 4; ++r) l[r] += tsum[r];

        bf16x8 ap0 = *(const bf16x8*)&Ps2[wave][col][quad * 8];
        bf16x8 ap1 = *(const bf16x8*)&Ps2[wave][col][32 + quad * 8];
        #pragma unroll
        for (int n = 0; n < 4; ++n) {
            bf16x8 b0 = *(const bf16x8*)&Vt[n * 16 + col][quad * 8];
            bf16x8 b1 = *(const bf16x8*)&Vt[n * 16 + col][32 + quad * 8];
            f32x4* op = (n == 0) ? &o0 : (n == 1) ? &o1 : (n == 2) ? &o2 : &o3;
            *op = __builtin_amdgcn_mfma_f32_16x16x32_bf16(ap0, b0, *op, 0, 0, 0);
            *op = __builtin_amdgcn_mfma_f32_16x16x32_bf16(ap1, b1, *op, 0, 0, 0);
        }
    }

    float inv[4];
    #pragma unroll
    for (int r = 0; r < 4; ++r) inv[r] = 1.0f / l[r];
    #pragma unroll
    for (int r = 0; r < 4; ++r) {
        long row = base + (long)(q0 + m0 + quad * 4 + r) * HD;
        O[row +  0 + col] = o0[r] * inv[r];
        O[row + 16 + col] = o1[r] * inv[r];
        O[row + 32 + col] = o2[r] * inv[r];
        O[row + 48 + col] = o3[r] * inv[r];
    }
}

extern "C" void kernel_launch(void* const* d_in, const int* in_sizes, int n_in,
                              void* d_out, int out_size, void* d_ws, size_t ws_size,
                              hipStream_t stream) {
    const float* Q = (const float*)d_in[0];
    const float* K = (const float*)d_in[1];
    const float* V = (const float*)d_in[2];
    float* O = (float*)d_out;

    const size_t tensorElems = (size_t)NHEADS * SEQ * HD;
    const size_t need = 2 * tensorElems * sizeof(unsigned short);

    if (ws_size >= need) {
        unsigned short* Kb  = (unsigned short*)d_ws;
        unsigned short* Vtb = Kb + tensorElems;
        const float qs = (float)(1.4426950408889634 / sqrt(2048.0));  // log2e/sqrt(S)
        prep_kv<<<dim3(NHEADS * (SEQ / 64)), dim3(256), 0, stream>>>(K, V, Kb, Vtb);
        fa_main<<<dim3(NHEADS * (SEQ / TQ)), dim3(256), 0, stream>>>(Q, Kb, Vtb, O, qs);
    } else {
        fa_fwd_fb<<<dim3(NHEADS * (SEQ / TQ)), dim3(256), 0, stream>>>(Q, K, V, O);
    }
}